// Round 8
// baseline (92.679 us; speedup 1.0000x reference)
//
#include <hip/hip_runtime.h>
#include <math.h>

// WeightedHausdorffDistance on MI355X — 2-dispatch version.
// B=8, H=W=256 (N=65536 pixels), M=128 points.
// main: 1024 blocks (128/batch, 4 waves/SIMD); per-block column-mins -> private
//       slot (no atomics/init); term1/focal partials per block.
// final: 1 block, fully parallel reduce.

#define HH 256
#define WW 256
#define NPIX (HH*WW)
#define MM 128
#define BB 8
#define MAXDIST 362.03867196751236f   // sqrt(256^2+256^2)
#define PBLK 128                       // blocks per batch -> 1024 blocks = 4 waves/SIMD
#define NBLK (BB*PBLK)
#define TPB 256                        // threads per block
#define PXT 2                          // pixels per thread (contiguous, same row)
#define MCH 16                         // m-chunk (register-resident)
#define NCH (MM/MCH)

#if defined(__has_builtin)
#if __has_builtin(__builtin_amdgcn_sqrtf)
#define FSQRT(x) __builtin_amdgcn_sqrtf(x)
#else
#define FSQRT(x) sqrtf(x)
#endif
#else
#define FSQRT(x) sqrtf(x)
#endif

__device__ __forceinline__ float wave_sum(float v) {
#pragma unroll
  for (int off = 32; off > 0; off >>= 1) v += __shfl_xor(v, off, 64);
  return v;
}

// ---- kernel 1: main fused pass
__global__ __launch_bounds__(TPB) void whd_main(
    const float* __restrict__ prob, const float* __restrict__ gtmap,
    const float* __restrict__ gt, const float* __restrict__ osz,
    float* __restrict__ partials, float* __restrict__ colminblk) {
  const int b   = blockIdx.x >> 7;          // / PBLK
  const int blk = blockIdx.x & (PBLK - 1);
  const int tid = threadIdx.x;
  const int lane = tid & 63;

  __shared__ float2 sgt[MM];
  __shared__ unsigned scm[MM];      // block-level column mins (uint bits, all vals >= 0)
  __shared__ float wred[TPB / 64][4];

  const float ny = osz[b * 2 + 0] * (1.0f / HH);
  const float nx = osz[b * 2 + 1] * (1.0f / WW);

  if (tid < MM) {
    float gy = gt[(b * MM + tid) * 2 + 0] * ny;
    float gx = gt[(b * MM + tid) * 2 + 1] * nx;
    sgt[tid] = make_float2(gy, gx);
    scm[tid] = 0x7F800000u;         // +inf
  }
  __syncthreads();

  const int pixBase = blk * (NPIX / PBLK) + tid * PXT;  // 512 pixels/block, 2 rows
  const float pyf = (float)(pixBase >> 8) * ny;         // row * norm_y
  const int col0 = pixBase & (WW - 1);

  const float* pp = prob + b * NPIX + pixBase;
  float2 pv = *(const float2*)(pp);
  float p[PXT] = {pv.x, pv.y};

  float pxf[PXT], bb[PXT], md[PXT];
#pragma unroll
  for (int i = 0; i < PXT; i++) {
    pxf[i] = (float)(col0 + i) * nx;
    bb[i]  = (1.0f - p[i]) * MAXDIST;   // (1-p)*MAX_DIST, hoisted
    md[i]  = 3.0e38f;                   // running min_m d
  }

#pragma unroll 1
  for (int c = 0; c < NCH; c++) {
    float gx[MCH], dy2[MCH], cm[MCH];
#pragma unroll
    for (int j = 0; j < MCH; j++) {
      float2 g = sgt[c * MCH + j];      // wave-uniform LDS read -> broadcast
      float dy = pyf - g.x;
      dy2[j] = dy * dy;                 // row shared by both pixels of this thread
      gx[j]  = g.y;
      cm[j]  = 3.0e38f;
    }
#pragma unroll
    for (int i = 0; i < PXT; i++) {
      const float pi = p[i], bi = bb[i], xi = pxf[i];
      float mdi = md[i];
#pragma unroll
      for (int j = 0; j < MCH; j++) {
        float dx = xi - gx[j];
        float d  = FSQRT(fmaf(dx, dx, dy2[j]));
        mdi   = fminf(mdi, d);                       // term1 row-min
        cm[j] = fminf(cm[j], fmaf(pi, d, bi));       // term2 column-min
      }
      md[i] = mdi;
    }

    // Transposed butterfly: reduce 16 column-mins over 64 lanes in-place.
    // After stages xor-32/16/8/4 + finish xor-1/2, lane l holds full wave min
    // for m = l>>2. min is exact & commutative -> deterministic.
    {
      const bool hi5 = (lane & 32) != 0;
#pragma unroll
      for (int k = 0; k < 8; k++) {
        float keep = hi5 ? cm[k + 8] : cm[k];
        float send = hi5 ? cm[k] : cm[k + 8];
        cm[k] = fminf(keep, __shfl_xor(send, 32, 64));
      }
      const bool hi4 = (lane & 16) != 0;
#pragma unroll
      for (int k = 0; k < 4; k++) {
        float keep = hi4 ? cm[k + 4] : cm[k];
        float send = hi4 ? cm[k] : cm[k + 4];
        cm[k] = fminf(keep, __shfl_xor(send, 16, 64));
      }
      const bool hi3 = (lane & 8) != 0;
#pragma unroll
      for (int k = 0; k < 2; k++) {
        float keep = hi3 ? cm[k + 2] : cm[k];
        float send = hi3 ? cm[k] : cm[k + 2];
        cm[k] = fminf(keep, __shfl_xor(send, 8, 64));
      }
      const bool hi2 = (lane & 4) != 0;
      {
        float keep = hi2 ? cm[1] : cm[0];
        float send = hi2 ? cm[0] : cm[1];
        cm[0] = fminf(keep, __shfl_xor(send, 4, 64));
      }
      float v = cm[0];
      v = fminf(v, __shfl_xor(v, 1, 64));
      v = fminf(v, __shfl_xor(v, 2, 64));
      // 16 writer lanes -> LDS atomicMin on distinct consecutive addresses
      // (4 waves may collide per address; LDS atomic handles it).
      if ((lane & 3) == 0)
        atomicMin(&scm[c * MCH + (lane >> 2)], __float_as_uint(v));
    }
  }

  // term1 partial sums
  float spd = 0.0f, sp = 0.0f;
#pragma unroll
  for (int i = 0; i < PXT; i++) {
    spd = fmaf(p[i], md[i], spd);
    sp += p[i];
  }

  // focal loss: only last batch's blocks touch gt_map
  float fs = 0.0f, fc = 0.0f;
  if (b == BB - 1) {
    const float* gp = gtmap + b * NPIX + pixBase;
    float2 gv2 = *(const float2*)(gp);
    float gv[PXT] = {gv2.x, gv2.y};
#pragma unroll
    for (int i = 0; i < PXT; i++) {
      float g = gv[i], pi = p[i];
      if (g == 1.0f) {
        float om = 1.0f - pi;
        fs += om * om * logf(pi);
        fc += 1.0f;
      } else {
        float t = 1.0f - g, t2 = t * t;
        fs += t2 * t2 * pi * pi * log1pf(-pi);
      }
    }
  }

  spd = wave_sum(spd);
  sp  = wave_sum(sp);
  fs  = wave_sum(fs);
  fc  = wave_sum(fc);

  const int wid = tid >> 6;
  if (lane == 0) {
    wred[wid][0] = spd; wred[wid][1] = sp; wred[wid][2] = fs; wred[wid][3] = fc;
  }
  __syncthreads();   // scm atomics + wred writes complete

  if (tid < MM)
    colminblk[blockIdx.x * MM + tid] = __uint_as_float(scm[tid]);  // coalesced
  if (tid == 0) {
    float a = 0, c2 = 0, e = 0, f = 0;
#pragma unroll
    for (int w = 0; w < TPB / 64; w++) {
      a += wred[w][0]; c2 += wred[w][1]; e += wred[w][2]; f += wred[w][3];
    }
    float* pt = partials + blockIdx.x * 4;
    pt[0] = a; pt[1] = c2; pt[2] = e; pt[3] = f;
  }
}

// ---- kernel 2: parallel final reduce (1 block)
__global__ __launch_bounds__(TPB) void whd_final(const float* __restrict__ colminblk,
                                                 const float* __restrict__ partials,
                                                 float* __restrict__ out) {
  const int tid = threadIdx.x;
  __shared__ float sT[TPB / 64];
  __shared__ float sA[BB], sC[BB], sF[BB], sG[BB];

  // term2: each thread owns 4 (batch,m) pairs: (b0+{0,2,4,6}, m).
  // Lanes read consecutive m -> coalesced; 4 independent chains, unroll 4.
  const int m  = tid & (MM - 1);
  const int b0 = tid >> 7;   // 0 or 1
  float mn0 = 3.0e38f, mn1 = 3.0e38f, mn2 = 3.0e38f, mn3 = 3.0e38f;
#pragma unroll 4
  for (int k = 0; k < PBLK; k++) {
    mn0 = fminf(mn0, colminblk[((b0 + 0) * PBLK + k) * MM + m]);
    mn1 = fminf(mn1, colminblk[((b0 + 2) * PBLK + k) * MM + m]);
    mn2 = fminf(mn2, colminblk[((b0 + 4) * PBLK + k) * MM + m]);
    mn3 = fminf(mn3, colminblk[((b0 + 6) * PBLK + k) * MM + m]);
  }
  float smin = (mn0 + mn1) + (mn2 + mn3);
  smin = wave_sum(smin);
  if ((tid & 63) == 0) sT[tid >> 6] = smin;

  // term1/focal: 32 threads per batch over that batch's 128 block partials
  const int g = tid >> 5;       // batch 0..7
  const int i = tid & 31;
  float a = 0, c = 0, e = 0, f = 0;
  for (int k = i; k < PBLK; k += 32) {
    const float* pt = partials + (g * PBLK + k) * 4;
    a += pt[0]; c += pt[1]; e += pt[2]; f += pt[3];
  }
#pragma unroll
  for (int off = 16; off > 0; off >>= 1) {
    a += __shfl_xor(a, off, 64); c += __shfl_xor(c, off, 64);
    e += __shfl_xor(e, off, 64); f += __shfl_xor(f, off, 64);
  }
  if (i == 0) { sA[g] = a; sC[g] = c; sF[g] = e; sG[g] = f; }
  __syncthreads();

  if (tid == 0) {
    float t2 = (sT[0] + sT[1] + sT[2] + sT[3]) * (1.0f / (BB * MM));
    float t1 = 0.0f;
    for (int b2 = 0; b2 < BB; b2++) t1 += sA[b2] / (sC[b2] + 1e-6f);
    t1 *= (1.0f / BB);
    float fsum = 0.0f, fcnt = 0.0f;
    for (int b2 = 0; b2 < BB; b2++) { fsum += sF[b2]; fcnt += sG[b2]; }
    out[0] = t1 + t2 - fsum / fcnt;   // -(focal_sum / pos_count)
  }
}

extern "C" void kernel_launch(void* const* d_in, const int* in_sizes, int n_in,
                              void* d_out, int out_size, void* d_ws, size_t ws_size,
                              hipStream_t stream) {
  const float* prob  = (const float*)d_in[0];  // [B,H,W]
  const float* gtmap = (const float*)d_in[1];  // [B,H,W]
  const float* gt    = (const float*)d_in[2];  // [B,M,2]
  const float* osz   = (const float*)d_in[3];  // [B,2]
  float* out = (float*)d_out;

  float* partials  = (float*)d_ws;                          // NBLK*4 floats (16 KB)
  float* colminblk = (float*)((char*)d_ws + NBLK * 16);     // NBLK*128 floats (512 KB)

  whd_main<<<NBLK, TPB, 0, stream>>>(prob, gtmap, gt, osz, partials, colminblk);
  whd_final<<<1, TPB, 0, stream>>>(colminblk, partials, out);
}